// Round 1
// baseline (397.423 us; speedup 1.0000x reference)
//
#include <hip/hip_runtime.h>

// Problem constants (B, L_IN, D) = (4, 4096, 1024)
#define BB 4
#define LL 4096
#define DD 1024
#define SS 64   // number of chunks in the scan
#define TT 64   // chunk length (SS*TT == LL)

typedef __attribute__((ext_vector_type(4))) float  floatx4;
typedef __attribute__((ext_vector_type(8))) short  shortx8;

static __device__ __forceinline__ unsigned short f2bf(float f) {
    unsigned int u = __float_as_uint(f);
    u += 0x7fffu + ((u >> 16) & 1u);           // round-to-nearest-even
    return (unsigned short)(u >> 16);
}
static __device__ __forceinline__ float bf2f(unsigned short h) {
    return __uint_as_float(((unsigned int)h) << 16);
}

// ---------------- f32 -> bf16 cast (vectorized) ----------------
__global__ void cast_bf16_kernel(const float4* __restrict__ src,
                                 ushort4* __restrict__ dst, int n4) {
    int i = blockIdx.x * blockDim.x + threadIdx.x;
    if (i < n4) {
        float4 v = src[i];
        ushort4 o;
        o.x = f2bf(v.x); o.y = f2bf(v.y); o.z = f2bf(v.z); o.w = f2bf(v.w);
        dst[i] = o;
    }
}

// ---------------- bf16 GEMM: C[M,N] = A[M,K] * B[N,K]^T + bias ----------------
// A row-major M x K (bf16), B row-major N x K (bf16).
// EPI==0: store bf16 (no relu). EPI==1: store f32 with relu.
// Block 256 threads (4 waves), tile 128x128, BK=32.
template<int K, int N, int EPI>
__global__ __launch_bounds__(256)
void gemm_bt(const unsigned short* __restrict__ A,
             const unsigned short* __restrict__ B,
             const float* __restrict__ bias,
             void* __restrict__ Cp) {
    __shared__ __align__(16) short As[128 * 32];
    __shared__ __align__(16) short Bs[128 * 32];

    const int tid   = threadIdx.x;
    const int tileN = blockIdx.x * 128;
    const int tileM = blockIdx.y * 128;
    const int lane  = tid & 63;
    const int wave  = tid >> 6;
    const int wm    = (wave >> 1) * 64;   // wave M offset within tile
    const int wn    = (wave & 1) * 64;    // wave N offset within tile
    const int r16   = lane & 15;
    const int quad  = lane >> 4;

    floatx4 acc[4][4] = {};

    // staging chunk indices: thread handles chunks {tid, tid+256} of A and of B
    const int q0 = tid, q1 = tid + 256;
    const int ra0 = q0 >> 2, ca0 = (q0 & 3) * 8;
    const int ra1 = q1 >> 2, ca1 = (q1 & 3) * 8;

    for (int k0 = 0; k0 < K; k0 += 32) {
        int4 av0 = *(const int4*)(&A[(size_t)(tileM + ra0) * K + k0 + ca0]);
        int4 av1 = *(const int4*)(&A[(size_t)(tileM + ra1) * K + k0 + ca1]);
        int4 bv0 = *(const int4*)(&B[(size_t)(tileN + ra0) * K + k0 + ca0]);
        int4 bv1 = *(const int4*)(&B[(size_t)(tileN + ra1) * K + k0 + ca1]);
        *(int4*)(&As[q0 * 8]) = av0;
        *(int4*)(&As[q1 * 8]) = av1;
        *(int4*)(&Bs[q0 * 8]) = bv0;
        *(int4*)(&Bs[q1 * 8]) = bv1;
        __syncthreads();

        shortx8 af[4], bfv[4];
#pragma unroll
        for (int i = 0; i < 4; ++i)
            af[i] = *(const shortx8*)(&As[(wm + i * 16 + r16) * 32 + quad * 8]);
#pragma unroll
        for (int j = 0; j < 4; ++j)
            bfv[j] = *(const shortx8*)(&Bs[(wn + j * 16 + r16) * 32 + quad * 8]);
#pragma unroll
        for (int i = 0; i < 4; ++i)
#pragma unroll
            for (int j = 0; j < 4; ++j)
                acc[i][j] = __builtin_amdgcn_mfma_f32_16x16x32_bf16(
                    af[i], bfv[j], acc[i][j], 0, 0, 0);
        __syncthreads();
    }

    // epilogue: C row = tileM + wm + i*16 + quad*4 + r ; col = tileN + wn + j*16 + r16
#pragma unroll
    for (int i = 0; i < 4; ++i) {
#pragma unroll
        for (int j = 0; j < 4; ++j) {
            const int col = tileN + wn + j * 16 + r16;
            const float bv = bias[col];
#pragma unroll
            for (int r = 0; r < 4; ++r) {
                const int row = tileM + wm + i * 16 + quad * 4 + r;
                float v = acc[i][j][r] + bv;
                if (EPI == 0) {
                    ((unsigned short*)Cp)[(size_t)row * N + col] = f2bf(v);
                } else {
                    ((float*)Cp)[(size_t)row * N + col] = fmaxf(v, 0.0f);
                }
            }
        }
    }
}

// ---------------- scan phase A: per-chunk local end values ----------------
// u: bf16 [B*L, 2D] (pairs re/im interleaved per channel). Eend: [SS][B*D] float2.
__global__ __launch_bounds__(256)
void scanA(const unsigned short* __restrict__ u,
           const float* __restrict__ plog,
           float2* __restrict__ Eend) {
    const int d = blockIdx.x * 256 + threadIdx.x;
    const int c = blockIdx.y, b = blockIdx.z;
    const float v  = expf(plog[d]);
    const float th = expf(plog[DD + d]);
    const float a  = expf(-v);
    const float lr = a * cosf(th), li = a * sinf(th);
    float zr = 0.f, zi = 0.f;
    const unsigned short* up = u + (size_t)(b * LL + c * TT) * (2 * DD) + 2 * d;
#pragma unroll 8
    for (int tl = 0; tl < TT; ++tl) {
        unsigned int pair = *(const unsigned int*)up;
        float xr_ = bf2f((unsigned short)(pair & 0xffffu));
        float xi_ = bf2f((unsigned short)(pair >> 16));
        float nzr = lr * zr - li * zi + xr_;
        float nzi = lr * zi + li * zr + xi_;
        zr = nzr; zi = nzi;
        up += 2 * DD;
    }
    Eend[(size_t)c * (BB * DD) + b * DD + d] = make_float2(zr, zi);
}

// ---------------- scan phase B: scan over chunk carries ----------------
__global__ __launch_bounds__(256)
void scanB(const float2* __restrict__ Eend,
           const float* __restrict__ plog,
           float2* __restrict__ Cin) {
    const int idx = blockIdx.x * 256 + threadIdx.x;  // b*DD + d
    const int d = idx & (DD - 1);
    const float v  = expf(plog[d]);
    const float th = expf(plog[DD + d]);
    const float a  = expf(-(float)TT * v);
    const float Lr = a * cosf((float)TT * th), Li = a * sinf((float)TT * th);
    float cr = 0.f, ci = 0.f;
    for (int c = 0; c < SS; ++c) {
        size_t o = (size_t)c * (BB * DD) + idx;
        Cin[o] = make_float2(cr, ci);
        float2 e = Eend[o];
        float ncr = Lr * cr - Li * ci + e.x;
        float nci = Lr * ci + Li * cr + e.y;
        cr = ncr; ci = nci;
    }
}

// ---------------- scan phase C: fix-up + gamma + emit xr (bf16) ----------------
// xr layout: [B*L, 2D] with col d = gamma*Re(y), col DD+d = gamma*Im(y)
__global__ __launch_bounds__(256)
void scanC(const unsigned short* __restrict__ u,
           const float* __restrict__ plog,
           const float2* __restrict__ Cin,
           unsigned short* __restrict__ xr) {
    const int d = blockIdx.x * 256 + threadIdx.x;
    const int c = blockIdx.y, b = blockIdx.z;
    const float v  = expf(plog[d]);
    const float th = expf(plog[DD + d]);
    const float g  = expf(plog[2 * DD + d]);
    const float a  = expf(-v);
    const float lr = a * cosf(th), li = a * sinf(th);
    float2 y0 = Cin[(size_t)c * (BB * DD) + b * DD + d];
    float yr = y0.x, yi = y0.y;
    const unsigned short* up = u + (size_t)(b * LL + c * TT) * (2 * DD) + 2 * d;
    unsigned short* xp = xr + (size_t)(b * LL + c * TT) * (2 * DD) + d;
#pragma unroll 4
    for (int tl = 0; tl < TT; ++tl) {
        unsigned int pair = *(const unsigned int*)up;
        float xr_ = bf2f((unsigned short)(pair & 0xffffu));
        float xi_ = bf2f((unsigned short)(pair >> 16));
        float nyr = lr * yr - li * yi + xr_;
        float nyi = lr * yi + li * yr + xi_;
        yr = nyr; yi = nyi;
        xp[0]  = f2bf(g * yr);
        xp[DD] = f2bf(g * yi);
        up += 2 * DD;
        xp += 2 * DD;
    }
}

extern "C" void kernel_launch(void* const* d_in, const int* in_sizes, int n_in,
                              void* d_out, int out_size, void* d_ws, size_t ws_size,
                              hipStream_t stream) {
    const float* inputs = (const float*)d_in[0];   // B*L*D = 16777216
    const float* Wi     = (const float*)d_in[1];   // 2D*D  = 2097152
    const float* bi     = (const float*)d_in[2];   // 2D
    const float* Wo     = (const float*)d_in[3];   // D*2D  = 2097152
    const float* bo     = (const float*)d_in[4];   // D
    const float* plog   = (const float*)d_in[5];   // 3*D
    float* out = (float*)d_out;

    const size_t M = (size_t)BB * LL;              // 16384
    unsigned short* u_bf  = (unsigned short*)d_ws;             // M*2D bf16  (64 MB)
    unsigned short* xr_bf = u_bf  + M * 2 * DD;                // M*2D bf16  (64 MB)
    unsigned short* in_bf = xr_bf + M * 2 * DD;                // M*D  bf16  (32 MB)
    unsigned short* Wi_bf = in_bf + M * DD;                    // 2D*D bf16  (4 MB)
    unsigned short* Wo_bf = Wi_bf + (size_t)2 * DD * DD;       // D*2D bf16  (4 MB)
    float2* Eend = (float2*)(Wo_bf + (size_t)2 * DD * DD);     // SS*B*D f32x2 (2 MB)
    float2* Cin  = Eend + (size_t)SS * BB * DD;                // SS*B*D f32x2 (2 MB)

    // casts to bf16
    {
        int n4 = (int)(M * DD / 4);
        cast_bf16_kernel<<<(n4 + 255) / 256, 256, 0, stream>>>(
            (const float4*)inputs, (ushort4*)in_bf, n4);
        int w4 = (int)(2 * DD * DD / 4);
        cast_bf16_kernel<<<(w4 + 255) / 256, 256, 0, stream>>>(
            (const float4*)Wi, (ushort4*)Wi_bf, w4);
        cast_bf16_kernel<<<(w4 + 255) / 256, 256, 0, stream>>>(
            (const float4*)Wo, (ushort4*)Wo_bf, w4);
    }

    // GEMM1: u[M, 2D] = in_bf[M, D] @ Wi^T + bi   (bf16 out)
    gemm_bt<DD, 2 * DD, 0><<<dim3(2 * DD / 128, M / 128), 256, 0, stream>>>(
        in_bf, Wi_bf, bi, (void*)u_bf);

    // scan
    scanA<<<dim3(DD / 256, SS, BB), 256, 0, stream>>>(u_bf, plog, Eend);
    scanB<<<(BB * DD) / 256, 256, 0, stream>>>(Eend, plog, Cin);
    scanC<<<dim3(DD / 256, SS, BB), 256, 0, stream>>>(u_bf, plog, Cin, xr_bf);

    // GEMM2: out[M, D] = relu(xr[M, 2D] @ Wo^T + bo)  (f32 out)
    gemm_bt<2 * DD, DD, 1><<<dim3(DD / 128, M / 128), 256, 0, stream>>>(
        xr_bf, Wo_bf, bo, (void*)out);
}

// Round 2
// 369.798 us; speedup vs baseline: 1.0747x; 1.0747x over previous
//
#include <hip/hip_runtime.h>

// Problem constants (B, L_IN, D) = (4, 4096, 1024)
#define BB 4
#define LL 4096
#define DD 1024
#define SS 64   // number of chunks in the scan
#define TT 64   // chunk length (SS*TT == LL)

typedef __attribute__((ext_vector_type(4))) float  floatx4;
typedef __attribute__((ext_vector_type(8))) short  shortx8;

static __device__ __forceinline__ unsigned short f2bf(float f) {
    unsigned int u = __float_as_uint(f);
    u += 0x7fffu + ((u >> 16) & 1u);           // round-to-nearest-even
    return (unsigned short)(u >> 16);
}
static __device__ __forceinline__ float bf2f(unsigned short h) {
    return __uint_as_float(((unsigned int)h) << 16);
}

// ---------------- f32 -> bf16 cast (vectorized) ----------------
__global__ void cast_bf16_kernel(const float4* __restrict__ src,
                                 ushort4* __restrict__ dst, int n4) {
    int i = blockIdx.x * blockDim.x + threadIdx.x;
    if (i < n4) {
        float4 v = src[i];
        ushort4 o;
        o.x = f2bf(v.x); o.y = f2bf(v.y); o.z = f2bf(v.z); o.w = f2bf(v.w);
        dst[i] = o;
    }
}

// ---------------- bf16 GEMM: C[M,N] = A[M,K] * B[N,K]^T + bias ----------------
// m97 structure: global_load_lds width=16 staging, 128x128 tile, BK=32,
// 4 waves x (4x4 of 16x16x32 MFMA).
// EPI==0: store bf16 (no relu). EPI==1: store f32 with relu.
template<int K, int N, int EPI>
__global__ __launch_bounds__(256)
void gemm_bt(const unsigned short* __restrict__ A,
             const unsigned short* __restrict__ B,
             const float* __restrict__ bias,
             void* __restrict__ Cp) {
    __shared__ __align__(16) short As[128 * 32];
    __shared__ __align__(16) short Bs[128 * 32];

    const int tid   = threadIdx.x;
    const int tileN = blockIdx.x * 128;
    const int tileM = blockIdx.y * 128;
    const int lane  = tid & 63;
    const int wave  = tid >> 6;
    const int wm    = (wave >> 1) * 64;   // wave M offset within tile
    const int wn    = (wave & 1) * 64;    // wave N offset within tile
    const int r16   = lane & 15;
    const int quad  = lane >> 4;

    floatx4 acc[4][4] = {};

    // staging chunks: 16B chunk q covers row=q>>2, k-chunk=(q&3)*8.
    // lane handles chunks q0=tid, q1=tid+256; LDS dest base (q&~63)*16 is
    // wave-uniform, lane writes base + lane*16 (global_load_lds constraint).
    const int q0 = tid, q1 = tid + 256;
    const int ra0 = q0 >> 2, ca0 = (q0 & 3) * 8;
    const int ra1 = q1 >> 2, ca1 = (q1 & 3) * 8;
    short* As0 = &As[(q0 & ~63) * 8];
    short* As1 = &As[(q1 & ~63) * 8];
    short* Bs0 = &Bs[(q0 & ~63) * 8];
    short* Bs1 = &Bs[(q1 & ~63) * 8];

    for (int k0 = 0; k0 < K; k0 += 32) {
        __builtin_amdgcn_global_load_lds(
            (const __attribute__((address_space(1))) void*)&A[(size_t)(tileM + ra0) * K + k0 + ca0],
            (__attribute__((address_space(3))) void*)As0, 16, 0, 0);
        __builtin_amdgcn_global_load_lds(
            (const __attribute__((address_space(1))) void*)&A[(size_t)(tileM + ra1) * K + k0 + ca1],
            (__attribute__((address_space(3))) void*)As1, 16, 0, 0);
        __builtin_amdgcn_global_load_lds(
            (const __attribute__((address_space(1))) void*)&B[(size_t)(tileN + ra0) * K + k0 + ca0],
            (__attribute__((address_space(3))) void*)Bs0, 16, 0, 0);
        __builtin_amdgcn_global_load_lds(
            (const __attribute__((address_space(1))) void*)&B[(size_t)(tileN + ra1) * K + k0 + ca1],
            (__attribute__((address_space(3))) void*)Bs1, 16, 0, 0);
        __syncthreads();   // compiler emits s_waitcnt vmcnt(0) before barrier

        shortx8 af[4], bfv[4];
#pragma unroll
        for (int i = 0; i < 4; ++i)
            af[i] = *(const shortx8*)(&As[(wm + i * 16 + r16) * 32 + quad * 8]);
#pragma unroll
        for (int j = 0; j < 4; ++j)
            bfv[j] = *(const shortx8*)(&Bs[(wn + j * 16 + r16) * 32 + quad * 8]);
#pragma unroll
        for (int i = 0; i < 4; ++i)
#pragma unroll
            for (int j = 0; j < 4; ++j)
                acc[i][j] = __builtin_amdgcn_mfma_f32_16x16x32_bf16(
                    af[i], bfv[j], acc[i][j], 0, 0, 0);
        __syncthreads();
    }

    // epilogue: C row = tileM + wm + i*16 + quad*4 + r ; col = tileN + wn + j*16 + r16
#pragma unroll
    for (int i = 0; i < 4; ++i) {
#pragma unroll
        for (int j = 0; j < 4; ++j) {
            const int col = tileN + wn + j * 16 + r16;
            const float bv = bias[col];
#pragma unroll
            for (int r = 0; r < 4; ++r) {
                const int row = tileM + wm + i * 16 + quad * 4 + r;
                float v = acc[i][j][r] + bv;
                if (EPI == 0) {
                    ((unsigned short*)Cp)[(size_t)row * N + col] = f2bf(v);
                } else {
                    ((float*)Cp)[(size_t)row * N + col] = fmaxf(v, 0.0f);
                }
            }
        }
    }
}

// ---------------- scan phase A: per-chunk local end values ----------------
// u: bf16 [B*L, 2D] (pairs re/im interleaved per channel). Eend: [SS][B*D] float2.
__global__ __launch_bounds__(256)
void scanA(const unsigned short* __restrict__ u,
           const float* __restrict__ plog,
           float2* __restrict__ Eend) {
    const int d = blockIdx.x * 256 + threadIdx.x;
    const int c = blockIdx.y, b = blockIdx.z;
    const float v  = expf(plog[d]);
    const float th = expf(plog[DD + d]);
    const float a  = expf(-v);
    const float lr = a * cosf(th), li = a * sinf(th);
    float zr = 0.f, zi = 0.f;
    const unsigned short* up = u + (size_t)(b * LL + c * TT) * (2 * DD) + 2 * d;
#pragma unroll 8
    for (int tl = 0; tl < TT; ++tl) {
        unsigned int pair = *(const unsigned int*)up;
        float xr_ = bf2f((unsigned short)(pair & 0xffffu));
        float xi_ = bf2f((unsigned short)(pair >> 16));
        float nzr = lr * zr - li * zi + xr_;
        float nzi = lr * zi + li * zr + xi_;
        zr = nzr; zi = nzi;
        up += 2 * DD;
    }
    Eend[(size_t)c * (BB * DD) + b * DD + d] = make_float2(zr, zi);
}

// ---------------- scan phase C: carry (inline prefix over Eend) + fix-up ----------------
// xr layout: [B*L, 2D] with col d = gamma*Re(y), col DD+d = gamma*Im(y)
__global__ __launch_bounds__(256)
void scanC(const unsigned short* __restrict__ u,
           const float* __restrict__ plog,
           const float2* __restrict__ Eend,
           unsigned short* __restrict__ xr) {
    const int d = blockIdx.x * 256 + threadIdx.x;
    const int c = blockIdx.y, b = blockIdx.z;
    const float v  = expf(plog[d]);
    const float th = expf(plog[DD + d]);
    const float g  = expf(plog[2 * DD + d]);
    const float a  = expf(-v);
    const float lr = a * cosf(th), li = a * sinf(th);

    // carry into chunk c: prefix over earlier chunks with Lambda = lambda^TT
    const float aT = expf(-(float)TT * v);
    const float Lr = aT * cosf((float)TT * th), Li = aT * sinf((float)TT * th);
    float yr = 0.f, yi = 0.f;
    for (int cc = 0; cc < c; ++cc) {
        float2 e = Eend[(size_t)cc * (BB * DD) + b * DD + d];
        float nyr = Lr * yr - Li * yi + e.x;
        float nyi = Lr * yi + Li * yr + e.y;
        yr = nyr; yi = nyi;
    }

    const unsigned short* up = u + (size_t)(b * LL + c * TT) * (2 * DD) + 2 * d;
    unsigned short* xp = xr + (size_t)(b * LL + c * TT) * (2 * DD) + d;
#pragma unroll 4
    for (int tl = 0; tl < TT; ++tl) {
        unsigned int pair = *(const unsigned int*)up;
        float xr_ = bf2f((unsigned short)(pair & 0xffffu));
        float xi_ = bf2f((unsigned short)(pair >> 16));
        float nyr = lr * yr - li * yi + xr_;
        float nyi = lr * yi + li * yr + xi_;
        yr = nyr; yi = nyi;
        xp[0]  = f2bf(g * yr);
        xp[DD] = f2bf(g * yi);
        up += 2 * DD;
        xp += 2 * DD;
    }
}

extern "C" void kernel_launch(void* const* d_in, const int* in_sizes, int n_in,
                              void* d_out, int out_size, void* d_ws, size_t ws_size,
                              hipStream_t stream) {
    const float* inputs = (const float*)d_in[0];   // B*L*D = 16777216
    const float* Wi     = (const float*)d_in[1];   // 2D*D  = 2097152
    const float* bi     = (const float*)d_in[2];   // 2D
    const float* Wo     = (const float*)d_in[3];   // D*2D  = 2097152
    const float* bo     = (const float*)d_in[4];   // D
    const float* plog   = (const float*)d_in[5];   // 3*D
    float* out = (float*)d_out;

    const size_t M = (size_t)BB * LL;              // 16384
    unsigned short* u_bf  = (unsigned short*)d_ws;             // M*2D bf16  (64 MB)
    unsigned short* xr_bf = u_bf  + M * 2 * DD;                // M*2D bf16  (64 MB)
    unsigned short* in_bf = xr_bf + M * 2 * DD;                // M*D  bf16  (32 MB)
    unsigned short* Wi_bf = in_bf + M * DD;                    // 2D*D bf16  (4 MB)
    unsigned short* Wo_bf = Wi_bf + (size_t)2 * DD * DD;       // D*2D bf16  (4 MB)
    float2* Eend = (float2*)(Wo_bf + (size_t)2 * DD * DD);     // SS*B*D f32x2 (2 MB)

    // casts to bf16
    {
        int n4 = (int)(M * DD / 4);
        cast_bf16_kernel<<<(n4 + 255) / 256, 256, 0, stream>>>(
            (const float4*)inputs, (ushort4*)in_bf, n4);
        int w4 = (int)(2 * DD * DD / 4);
        cast_bf16_kernel<<<(w4 + 255) / 256, 256, 0, stream>>>(
            (const float4*)Wi, (ushort4*)Wi_bf, w4);
        cast_bf16_kernel<<<(w4 + 255) / 256, 256, 0, stream>>>(
            (const float4*)Wo, (ushort4*)Wo_bf, w4);
    }

    // GEMM1: u[M, 2D] = in_bf[M, D] @ Wi^T + bi   (bf16 out)
    gemm_bt<DD, 2 * DD, 0><<<dim3(2 * DD / 128, M / 128), 256, 0, stream>>>(
        in_bf, Wi_bf, bi, (void*)u_bf);

    // scan (2-pass chunked; carries computed inline in scanC)
    scanA<<<dim3(DD / 256, SS, BB), 256, 0, stream>>>(u_bf, plog, Eend);
    scanC<<<dim3(DD / 256, SS, BB), 256, 0, stream>>>(u_bf, plog, Eend, xr_bf);

    // GEMM2: out[M, D] = relu(xr[M, 2D] @ Wo^T + bo)  (f32 out)
    gemm_bt<2 * DD, DD, 1><<<dim3(DD / 128, M / 128), 256, 0, stream>>>(
        xr_bf, Wo_bf, bo, (void*)out);
}

// Round 3
// 351.556 us; speedup vs baseline: 1.1305x; 1.0519x over previous
//
#include <hip/hip_runtime.h>

// Problem constants (B, L_IN, D) = (4, 4096, 1024)
#define BB 4
#define LL 4096
#define DD 1024
#define SS 64   // number of chunks in the scan
#define TT 64   // chunk length (SS*TT == LL)

typedef __attribute__((ext_vector_type(4))) float  floatx4;
typedef __attribute__((ext_vector_type(8))) short  shortx8;

static __device__ __forceinline__ unsigned short f2bf(float f) {
    unsigned int u = __float_as_uint(f);
    u += 0x7fffu + ((u >> 16) & 1u);           // round-to-nearest-even
    return (unsigned short)(u >> 16);
}
static __device__ __forceinline__ float bf2f(unsigned short h) {
    return __uint_as_float(((unsigned int)h) << 16);
}

// ---------------- f32 -> bf16 cast (vectorized) ----------------
__global__ void cast_bf16_kernel(const float4* __restrict__ src,
                                 ushort4* __restrict__ dst, int n4) {
    int i = blockIdx.x * blockDim.x + threadIdx.x;
    if (i < n4) {
        float4 v = src[i];
        ushort4 o;
        o.x = f2bf(v.x); o.y = f2bf(v.y); o.z = f2bf(v.z); o.w = f2bf(v.w);
        dst[i] = o;
    }
}

// ---------------- bf16 GEMM: C[M,N] = A[M,K] * B[N,K]^T + bias ----------------
// m97 structure + (a) XOR-swizzled LDS chunk layout so ds_read_b128 fragment
// reads are bank-conflict-free, (b) XCD-aware 1D block remap so all blocks
// sharing an A M-tile land on the same XCD's L2.
// LDS chunk q (16B) holds row=q>>2, k8 = (q&3) ^ ((row>>1)&3).
// EPI==0: store bf16 (no relu). EPI==1: store f32 with relu.
template<int K, int NT, int EPI>
__global__ __launch_bounds__(256)
void gemm_bt(const unsigned short* __restrict__ A,
             const unsigned short* __restrict__ B,
             const float* __restrict__ bias,
             void* __restrict__ Cp) {
    constexpr int N = NT * 128;
    __shared__ __align__(16) short As[128 * 32];
    __shared__ __align__(16) short Bs[128 * 32];

    const int tid = threadIdx.x;
    // XCD-aware remap: blocks with equal (b&7) go to the same XCD (round-robin
    // heuristic); enumerate that XCD's blocks as (M-tile group, all N-tiles).
    const int b   = blockIdx.x;
    const int xcd = b & 7;
    const int i2  = b >> 3;
    const int tileM = ((i2 / NT) * 8 + xcd) * 128;
    const int tileN = (i2 % NT) * 128;

    const int lane  = tid & 63;
    const int wave  = tid >> 6;
    const int wm    = (wave >> 1) * 64;   // wave M offset within tile
    const int wn    = (wave & 1) * 64;    // wave N offset within tile
    const int r16   = lane & 15;
    const int quad  = lane >> 4;

    floatx4 acc[4][4] = {};

    // staging: lane handles chunks q0=tid, q1=tid+256. Chunk q -> LDS offset
    // q*16B (wave-uniform base + lane*16, global_load_lds constraint); global
    // source = row q>>2, k-chunk (q&3)^((row>>1)&3)  [XOR swizzle].
    const int q0 = tid, q1 = tid + 256;
    const int ra0 = q0 >> 2, ca0 = ((q0 & 3) ^ ((ra0 >> 1) & 3)) * 8;
    const int ra1 = q1 >> 2, ca1 = ((q1 & 3) ^ ((ra1 >> 1) & 3)) * 8;
    short* As0 = &As[(q0 & ~63) * 8];
    short* As1 = &As[(q1 & ~63) * 8];
    short* Bs0 = &Bs[(q0 & ~63) * 8];
    short* Bs1 = &Bs[(q1 & ~63) * 8];

    // fragment-read swizzle: slot = quad ^ ((r16>>1)&3), in shorts *8
    const int fsw = (quad ^ ((r16 >> 1) & 3)) * 8;

    for (int k0 = 0; k0 < K; k0 += 32) {
        __builtin_amdgcn_global_load_lds(
            (const __attribute__((address_space(1))) void*)&A[(size_t)(tileM + ra0) * K + k0 + ca0],
            (__attribute__((address_space(3))) void*)As0, 16, 0, 0);
        __builtin_amdgcn_global_load_lds(
            (const __attribute__((address_space(1))) void*)&A[(size_t)(tileM + ra1) * K + k0 + ca1],
            (__attribute__((address_space(3))) void*)As1, 16, 0, 0);
        __builtin_amdgcn_global_load_lds(
            (const __attribute__((address_space(1))) void*)&B[(size_t)(tileN + ra0) * K + k0 + ca0],
            (__attribute__((address_space(3))) void*)Bs0, 16, 0, 0);
        __builtin_amdgcn_global_load_lds(
            (const __attribute__((address_space(1))) void*)&B[(size_t)(tileN + ra1) * K + k0 + ca1],
            (__attribute__((address_space(3))) void*)Bs1, 16, 0, 0);
        __syncthreads();

        shortx8 af[4], bfv[4];
#pragma unroll
        for (int i = 0; i < 4; ++i)
            af[i] = *(const shortx8*)(&As[(wm + i * 16 + r16) * 32 + fsw]);
#pragma unroll
        for (int j = 0; j < 4; ++j)
            bfv[j] = *(const shortx8*)(&Bs[(wn + j * 16 + r16) * 32 + fsw]);
#pragma unroll
        for (int i = 0; i < 4; ++i)
#pragma unroll
            for (int j = 0; j < 4; ++j)
                acc[i][j] = __builtin_amdgcn_mfma_f32_16x16x32_bf16(
                    af[i], bfv[j], acc[i][j], 0, 0, 0);
        __syncthreads();
    }

    // epilogue: C row = tileM + wm + i*16 + quad*4 + r ; col = tileN + wn + j*16 + r16
#pragma unroll
    for (int i = 0; i < 4; ++i) {
#pragma unroll
        for (int j = 0; j < 4; ++j) {
            const int col = tileN + wn + j * 16 + r16;
            const float bv = bias[col];
#pragma unroll
            for (int r = 0; r < 4; ++r) {
                const int row = tileM + wm + i * 16 + quad * 4 + r;
                float v = acc[i][j][r] + bv;
                if (EPI == 0) {
                    ((unsigned short*)Cp)[(size_t)row * N + col] = f2bf(v);
                } else {
                    ((float*)Cp)[(size_t)row * N + col] = fmaxf(v, 0.0f);
                }
            }
        }
    }
}

// ---------------- scan phase A: per-chunk local end values ----------------
// u: bf16 [B*L, 2D] (pairs re/im interleaved per channel). Eend: [SS][B*D] float2.
__global__ __launch_bounds__(256)
void scanA(const unsigned short* __restrict__ u,
           const float* __restrict__ plog,
           float2* __restrict__ Eend) {
    const int d = blockIdx.x * 256 + threadIdx.x;
    const int c = blockIdx.y, b = blockIdx.z;
    const float v  = expf(plog[d]);
    const float th = expf(plog[DD + d]);
    const float a  = expf(-v);
    const float lr = a * cosf(th), li = a * sinf(th);
    float zr = 0.f, zi = 0.f;
    const unsigned short* up = u + (size_t)(b * LL + c * TT) * (2 * DD) + 2 * d;
#pragma unroll 8
    for (int tl = 0; tl < TT; ++tl) {
        unsigned int pair = *(const unsigned int*)up;
        float xr_ = bf2f((unsigned short)(pair & 0xffffu));
        float xi_ = bf2f((unsigned short)(pair >> 16));
        float nzr = lr * zr - li * zi + xr_;
        float nzi = lr * zi + li * zr + xi_;
        zr = nzr; zi = nzi;
        up += 2 * DD;
    }
    Eend[(size_t)c * (BB * DD) + b * DD + d] = make_float2(zr, zi);
}

// ---------------- scan phase C: carry (inline prefix over Eend) + fix-up ----------------
// xr layout: [B*L, 2D] with col d = gamma*Re(y), col DD+d = gamma*Im(y)
__global__ __launch_bounds__(256)
void scanC(const unsigned short* __restrict__ u,
           const float* __restrict__ plog,
           const float2* __restrict__ Eend,
           unsigned short* __restrict__ xr) {
    const int d = blockIdx.x * 256 + threadIdx.x;
    const int c = blockIdx.y, b = blockIdx.z;
    const float v  = expf(plog[d]);
    const float th = expf(plog[DD + d]);
    const float g  = expf(plog[2 * DD + d]);
    const float a  = expf(-v);
    const float lr = a * cosf(th), li = a * sinf(th);

    // carry into chunk c: prefix over earlier chunks with Lambda = lambda^TT
    const float aT = expf(-(float)TT * v);
    const float Lr = aT * cosf((float)TT * th), Li = aT * sinf((float)TT * th);
    float yr = 0.f, yi = 0.f;
    for (int cc = 0; cc < c; ++cc) {
        float2 e = Eend[(size_t)cc * (BB * DD) + b * DD + d];
        float nyr = Lr * yr - Li * yi + e.x;
        float nyi = Lr * yi + Li * yr + e.y;
        yr = nyr; yi = nyi;
    }

    const unsigned short* up = u + (size_t)(b * LL + c * TT) * (2 * DD) + 2 * d;
    unsigned short* xp = xr + (size_t)(b * LL + c * TT) * (2 * DD) + d;
#pragma unroll 4
    for (int tl = 0; tl < TT; ++tl) {
        unsigned int pair = *(const unsigned int*)up;
        float xr_ = bf2f((unsigned short)(pair & 0xffffu));
        float xi_ = bf2f((unsigned short)(pair >> 16));
        float nyr = lr * yr - li * yi + xr_;
        float nyi = lr * yi + li * yr + xi_;
        yr = nyr; yi = nyi;
        xp[0]  = f2bf(g * yr);
        xp[DD] = f2bf(g * yi);
        up += 2 * DD;
        xp += 2 * DD;
    }
}

extern "C" void kernel_launch(void* const* d_in, const int* in_sizes, int n_in,
                              void* d_out, int out_size, void* d_ws, size_t ws_size,
                              hipStream_t stream) {
    const float* inputs = (const float*)d_in[0];   // B*L*D = 16777216
    const float* Wi     = (const float*)d_in[1];   // 2D*D  = 2097152
    const float* bi     = (const float*)d_in[2];   // 2D
    const float* Wo     = (const float*)d_in[3];   // D*2D  = 2097152
    const float* bo     = (const float*)d_in[4];   // D
    const float* plog   = (const float*)d_in[5];   // 3*D
    float* out = (float*)d_out;

    const size_t M = (size_t)BB * LL;              // 16384
    unsigned short* u_bf  = (unsigned short*)d_ws;             // M*2D bf16  (64 MB)
    unsigned short* xr_bf = u_bf  + M * 2 * DD;                // M*2D bf16  (64 MB)
    unsigned short* in_bf = xr_bf + M * 2 * DD;                // M*D  bf16  (32 MB)
    unsigned short* Wi_bf = in_bf + M * DD;                    // 2D*D bf16  (4 MB)
    unsigned short* Wo_bf = Wi_bf + (size_t)2 * DD * DD;       // D*2D bf16  (4 MB)
    float2* Eend = (float2*)(Wo_bf + (size_t)2 * DD * DD);     // SS*B*D f32x2 (2 MB)

    // casts to bf16
    {
        int n4 = (int)(M * DD / 4);
        cast_bf16_kernel<<<(n4 + 255) / 256, 256, 0, stream>>>(
            (const float4*)inputs, (ushort4*)in_bf, n4);
        int w4 = (int)(2 * DD * DD / 4);
        cast_bf16_kernel<<<(w4 + 255) / 256, 256, 0, stream>>>(
            (const float4*)Wi, (ushort4*)Wi_bf, w4);
        cast_bf16_kernel<<<(w4 + 255) / 256, 256, 0, stream>>>(
            (const float4*)Wo, (ushort4*)Wo_bf, w4);
    }

    // GEMM1: u[M, 2D] = in_bf[M, D] @ Wi^T + bi   (bf16 out), NT = 2048/128 = 16
    gemm_bt<DD, 16, 0><<<(M / 128) * 16, 256, 0, stream>>>(
        in_bf, Wi_bf, bi, (void*)u_bf);

    // scan (2-pass chunked; carries computed inline in scanC)
    scanA<<<dim3(DD / 256, SS, BB), 256, 0, stream>>>(u_bf, plog, Eend);
    scanC<<<dim3(DD / 256, SS, BB), 256, 0, stream>>>(u_bf, plog, Eend, xr_bf);

    // GEMM2: out[M, D] = relu(xr[M, 2D] @ Wo^T + bo)  (f32 out), NT = 1024/128 = 8
    gemm_bt<2 * DD, 8, 1><<<(M / 128) * 8, 256, 0, stream>>>(
        xr_bf, Wo_bf, bo, (void*)out);
}